// Round 9
// baseline (265.507 us; speedup 1.0000x reference)
//
#include <hip/hip_runtime.h>

// ---------------------------------------------------------------------------
// Attention block: out = (softmax((q Wq^T+bq)(k Wk^T+bk)^T / 8) (v Wv^T+bv)) Wo^T + bo
// B=4 T=2048 C=1024 H=16 CH=64.  Internal compute bf16 MFMA + f32 accum.
// R8: GEMM weights read directly from global (L2-resident) into MFMA
//     fragments -- no weight LDS, no glds drain; act LDS dbuf 32KB -> 3
//     blocks/CU.  gemm_out same treatment.  Attn unchanged.
// ---------------------------------------------------------------------------

typedef short bf8 __attribute__((ext_vector_type(8)));      // 8 bf16 (4 VGPRs)
typedef float f4 __attribute__((ext_vector_type(4)));
typedef float f16v __attribute__((ext_vector_type(16)));
typedef unsigned short u16;

#define AS1 __attribute__((address_space(1)))
#define AS3 __attribute__((address_space(3)))

__device__ __forceinline__ u16 f2b(float f) {
  unsigned u = __builtin_bit_cast(unsigned, f);
  u += 0x7FFFu + ((u >> 16) & 1u);          // RNE
  return (u16)(u >> 16);
}

__device__ __forceinline__ unsigned cvtpk(float lo, float hi) {
  unsigned r;
  asm("v_cvt_pk_bf16_f32 %0, %1, %2" : "=v"(r) : "v"(lo), "v"(hi));
  return r;
}

__device__ __forceinline__ void swap32(unsigned& a, unsigned& b) {
  asm("v_permlane32_swap_b32 %0, %1" : "+v"(a), "+v"(b));
}

// ---------------- fused weight converts (4 x 1024x1024 fp32 -> bf16) --------
__global__ void cvt4_kernel(const float* __restrict__ a, const float* __restrict__ b,
                            const float* __restrict__ c, const float* __restrict__ d,
                            u16* __restrict__ out) {
  int i = blockIdx.x * blockDim.x + threadIdx.x;     // i in [0, 4*2^18)
  const int sel = i >> 18, off = i & 0x3FFFF;
  const float* src = sel == 0 ? a : sel == 1 ? b : sel == 2 ? c : d;
  float4 f = ((const float4*)src)[off];
  ushort4 o;
  o.x = f2b(f.x); o.y = f2b(f.y); o.z = f2b(f.z); o.w = f2b(f.w);
  ((ushort4*)out)[i] = o;
}

// ---------------- epilogues ----------------
template<int MODE>
__device__ __forceinline__ void gemm_epilogue(
    f4 (&acc)[4][4], const float* __restrict__ bias, void* __restrict__ Cout,
    int N, float scale, int m0, int n0, int wm, int wn, int lr, int lg)
{
  if (MODE == 0) {
    float bv[4];
    #pragma unroll
    for (int j = 0; j < 4; ++j) bv[j] = bias[n0 + wn + j * 16 + lr];
    float* C = (float*)Cout;
    #pragma unroll
    for (int i = 0; i < 4; ++i)
      #pragma unroll
      for (int j = 0; j < 4; ++j) {
        const int col = n0 + wn + j * 16 + lr;
        #pragma unroll
        for (int r = 0; r < 4; ++r) {
          const int row = m0 + wm + i * 16 + lg * 4 + r;
          C[(size_t)row * N + col] = acc[i][j][r] + bv[j];
        }
      }
  } else if (MODE == 1) {
    float bv[4];
    #pragma unroll
    for (int j = 0; j < 4; ++j) bv[j] = bias[n0 + wn + j * 16 + lr];
    u16* C = (u16*)Cout;
    #pragma unroll
    for (int i = 0; i < 4; ++i)
      #pragma unroll
      for (int j = 0; j < 4; ++j) {
        const int col = n0 + wn + j * 16 + lr;     // n = h*64+ch
        const int h = col >> 6, ch = col & 63;
        #pragma unroll
        for (int r = 0; r < 4; ++r) {
          const int row = m0 + wm + i * 16 + lg * 4 + r;  // m = b*2048+t
          const int b = row >> 11, t = row & 2047;
          C[((size_t)(b * 16 + h) * 2048 + t) * 64 + ch] = f2b((acc[i][j][r] + bv[j]) * scale);
        }
      }
  } else {
    u16* C = (u16*)Cout;
    #pragma unroll
    for (int i = 0; i < 4; ++i)
      #pragma unroll
      for (int r = 0; r < 4; ++r) {
        const int nch = m0 + wm + i * 16 + lg * 4 + r;
        const float br = bias[nch];
        const int h = nch >> 6, ch = nch & 63;
        #pragma unroll
        for (int j = 0; j < 4; ++j) {
          const int tok = n0 + wn + j * 16 + lr;
          const int b = tok >> 11, t = tok & 2047;
          C[((size_t)((b * 16 + h) * 64 + ch) << 11) + t] = f2b(acc[i][j][r] + br);
        }
      }
  }
}

// ---------------- pipelined fp-act GEMM body (weights direct from L2) --------
// ACTB=0: A = fp32 act (tile rows m), B = bf16 weights (direct global).
// ACTB=1: A = bf16 weights (direct), B = fp32 act (tile rows n).
// Act staged in LDS actT[2][8192] u16 (XOR-swizzled), 2-deep reg prefetch,
// one __syncthreads per K-step.
template<int MODE, int ACTB>
__device__ __forceinline__ void gemm_fp_body(
    u16* __restrict__ actT,
    const float* __restrict__ act, const u16* __restrict__ Wt,
    const float* __restrict__ bias, void* __restrict__ Cout,
    int N, int K, float scale, int m0, int n0)
{
  const int tid = threadIdx.x, lane = tid & 63, w = tid >> 6;
  const int wm = (w >> 1) << 6, wn = (w & 1) << 6;
  const int lr = lane & 15, lg = lane >> 4;
  const int arow0 = (ACTB ? n0 : m0);       // act global row base
  const int wrow0 = (ACTB ? m0 : n0);       // weight global row base
  const int wloc  = (ACTB ? wm : wn);       // weight local row base
  const int aloc  = (ACTB ? wn : wm);       // act local row base

  f4 acc[4][4] = {};
  float4 ta[8];

  // per-thread act chunk ids: c = w*256 + q*64 + lane
  #define ACT_LOAD(karg)                                                        \
    do {                                                                        \
      const int k_ = (karg);                                                    \
      _Pragma("unroll")                                                         \
      for (int q = 0; q < 4; ++q) {                                             \
        const int c = (w << 8) + (q << 6) + lane;                               \
        const int row = c >> 3, col = (c & 7) << 3;                             \
        const float* s = act + (size_t)(arow0 + row) * K + k_ + col;            \
        ta[2 * q] = *(const float4*)s;                                          \
        ta[2 * q + 1] = *(const float4*)(s + 4);                                \
      }                                                                         \
    } while (0)

  #define ACT_WRITE(buf)                                                        \
    do {                                                                        \
      u16* dst = actT + ((buf) << 13);                                          \
      _Pragma("unroll")                                                         \
      for (int q = 0; q < 4; ++q) {                                             \
        const int c = (w << 8) + (q << 6) + lane;                               \
        const int row = c >> 3;                                                 \
        uint4 pk;                                                               \
        pk.x = cvtpk(ta[2 * q].x, ta[2 * q].y);                                 \
        pk.y = cvtpk(ta[2 * q].z, ta[2 * q].w);                                 \
        pk.z = cvtpk(ta[2 * q + 1].x, ta[2 * q + 1].y);                         \
        pk.w = cvtpk(ta[2 * q + 1].z, ta[2 * q + 1].w);                         \
        *(uint4*)(dst + (row << 6) + (((c & 7) ^ (row & 7)) << 3)) = pk;        \
      }                                                                         \
    } while (0)

  // prologue: act(0) -> buf0; act(1) -> regs
  ACT_LOAD(0);
  ACT_WRITE(0);
  ACT_LOAD(64);
  __syncthreads();

  const int NKT = K >> 6;
  for (int kt = 0; kt < NKT; ++kt) {
    const int cur = kt & 1;
    const u16* aC = actT + (cur << 13);

    if (kt + 1 < NKT) {
      ACT_WRITE(cur ^ 1);
      if (kt + 2 < NKT) ACT_LOAD((kt + 2) << 6);
    }

    const int kb = kt << 6;
    #pragma unroll
    for (int ks = 0; ks < 2; ++ks) {
      bf8 actf[4], wf[4];
      #pragma unroll
      for (int i = 0; i < 4; ++i) {
        const int ral = aloc + i * 16 + lr;                     // act local row
        actf[i] = *(const bf8*)(aC + (ral << 6) + ((((ks << 2) + lg) ^ (ral & 7)) << 3));
        const int rwg = wrow0 + wloc + i * 16 + lr;             // weight global row
        wf[i] = *(const bf8*)(Wt + (size_t)rwg * K + kb + ks * 32 + lg * 8);
      }
      __builtin_amdgcn_s_setprio(1);
      #pragma unroll
      for (int i = 0; i < 4; ++i)
        #pragma unroll
        for (int j = 0; j < 4; ++j) {
          // A-operand rows = m-tile, B-operand rows = n-tile
          if (ACTB)
            acc[i][j] = __builtin_amdgcn_mfma_f32_16x16x32_bf16(wf[i], actf[j], acc[i][j], 0, 0, 0);
          else
            acc[i][j] = __builtin_amdgcn_mfma_f32_16x16x32_bf16(actf[i], wf[j], acc[i][j], 0, 0, 0);
        }
      __builtin_amdgcn_s_setprio(0);
    }
    __syncthreads();
  }
  #undef ACT_LOAD
  #undef ACT_WRITE

  gemm_epilogue<MODE>(acc, bias, Cout, N, scale, m0, n0, wm, wn, lr, lg);
}

// ---------------- merged QKV projection dispatch (1536 blocks) ----------------
__global__ __launch_bounds__(256, 3)
void proj_qkv(const float* __restrict__ q_in, const float* __restrict__ k_in,
              const float* __restrict__ v_in,
              const u16* __restrict__ Wq, const u16* __restrict__ Wk,
              const u16* __restrict__ Wv,
              const float* __restrict__ bq, const float* __restrict__ bk,
              const float* __restrict__ bv,
              u16* __restrict__ Qp, u16* __restrict__ Kp, u16* __restrict__ Vt,
              float qscale)
{
  __shared__ __align__(16) u16 actT[16384];     // 32 KB: 2 x 16KB act dbuf

  const int cpx = gridDim.x >> 3;
  const int bid = (blockIdx.x & 7) * cpx + (blockIdx.x >> 3);
  const int which = bid >> 9, sub = bid & 511;

  if (which < 2) {
    // Q/K proj: 64 token m-panels x 8 weight n-panels (n fastest -> act L2 reuse)
    gemm_fp_body<1, 0>(actT,
                       which ? k_in : q_in,
                       which ? Wk : Wq,
                       which ? bk : bq,
                       which ? (void*)Kp : (void*)Qp,
                       1024, 1024, which ? 1.f : qscale,
                       (sub >> 3) << 7, (sub & 7) << 7);
  } else {
    // V proj: 8 weight m-panels (fastest) x 64 token n-panels
    gemm_fp_body<2, 1>(actT, v_in, Wv, bv, (void*)Vt,
                       8192, 1024, 1.f, (sub & 7) << 7, (sub >> 3) << 7);
  }
}

// ---------------- output projection (Oc via glds dbuf, Wo direct) ------------
__global__ __launch_bounds__(256, 3)
void gemm_out(const u16* __restrict__ A, const u16* __restrict__ B,
              const float* __restrict__ bias, float* __restrict__ C)
{
  __shared__ __align__(16) u16 aT[16384];       // 2 x 16KB dbuf for A (Oc)

  const int cpx = gridDim.x >> 3;
  const int bid = (blockIdx.x & 7) * cpx + (blockIdx.x >> 3);
  const int m0 = (bid >> 3) << 7, n0 = (bid & 7) << 7;
  const int tid = threadIdx.x, lane = tid & 63, w = tid >> 6;
  const int wm = (w >> 1) << 6, wn = (w & 1) << 6;
  const int lr = lane & 15, lg = lane >> 4;
  const int K = 1024;

  f4 acc[4][4] = {};

  #define A_STAGE(buf, karg)                                                    \
    do {                                                                        \
      const int k_ = (karg);                                                    \
      u16* dst = aT + ((buf) << 13);                                            \
      _Pragma("unroll")                                                         \
      for (int q = 0; q < 4; ++q) {                                             \
        const int c = (w << 8) + (q << 6) + lane;                               \
        const int row = c >> 3, sw = ((c & 7) ^ (row & 7)) << 3;                \
        __builtin_amdgcn_global_load_lds(                                       \
            (const AS1 void*)(A + (size_t)(m0 + row) * K + k_ + sw),            \
            (AS3 void*)(dst + (((w << 2) + q) << 9)), 16, 0, 0);                \
      }                                                                         \
    } while (0)

  A_STAGE(0, 0);
  __syncthreads();

  for (int kt = 0; kt < 16; ++kt) {
    const int cur = kt & 1;
    const u16* aC = aT + (cur << 13);
    if (kt + 1 < 16) A_STAGE(cur ^ 1, (kt + 1) << 6);

    const int kb = kt << 6;
    #pragma unroll
    for (int ks = 0; ks < 2; ++ks) {
      bf8 af[4], bfr[4];
      #pragma unroll
      for (int i = 0; i < 4; ++i) {
        const int ra = wm + i * 16 + lr;
        af[i] = *(const bf8*)(aC + (ra << 6) + ((((ks << 2) + lg) ^ (ra & 7)) << 3));
        const int rb = n0 + wn + i * 16 + lr;
        bfr[i] = *(const bf8*)(B + (size_t)rb * K + kb + ks * 32 + lg * 8);
      }
      __builtin_amdgcn_s_setprio(1);
      #pragma unroll
      for (int i = 0; i < 4; ++i)
        #pragma unroll
        for (int j = 0; j < 4; ++j)
          acc[i][j] = __builtin_amdgcn_mfma_f32_16x16x32_bf16(af[i], bfr[j], acc[i][j], 0, 0, 0);
      __builtin_amdgcn_s_setprio(0);
    }
    __syncthreads();
  }
  #undef A_STAGE

  gemm_epilogue<0>(acc, bias, (void*)C, 1024, 1.f, m0, n0, wm, wn, lr, lg);
}

// ---------------- flash attention (32x32 MFMA, in-register P, pipelined) -----
// grid 1024 (XCD-mapped), 256 threads = 4 waves x 32 q.
// Q (pre-scaled by 0.125*log2e), K in [B,H,T,CH]; V^T in [B,H,CH,T]; O in [B,T,C].
__global__ __launch_bounds__(256, 4)
void attn_kernel(const u16* __restrict__ Qp, const u16* __restrict__ Kp,
                 const u16* __restrict__ VT, u16* __restrict__ Ob)
{
  __shared__ __align__(16) u16 pool[16384];     // 32 KB: kt[2][4096] | vt[2][4096]; reused as ot[128][72]
  u16* const ktb = pool;
  u16* const vtb = pool + 8192;

  const int flat = blockIdx.x;
  const int xcd = flat & 7, idx = flat >> 3;
  const int bh = (xcd << 3) + (idx >> 4);
  const int tq0 = (idx & 15) << 7;

  const int tid = threadIdx.x, lane = tid & 63, w = tid >> 6;
  const int ql = lane & 31, hi = lane >> 5;
  const size_t hoff = (size_t)bh * (2048 * 64);
  const u16* Kh = Kp + hoff;
  const u16* Vh = VT + hoff;

  bf8 qf[4];
  {
    const u16* qp_ = Qp + hoff + (size_t)(tq0 + w * 32 + ql) * 64 + hi * 8;
    #pragma unroll
    for (int ks = 0; ks < 4; ++ks) qf[ks] = *(const bf8*)(qp_ + 16 * ks);
  }

  f16v o0 = {}, o1 = {};
  float lrun = 0.f;

  const int c0i = (w << 7) + lane;
  const int c1i = c0i + 64;
  const int sr0 = c0i >> 3, ss0 = ((c0i & 7) ^ (sr0 & 7)) << 3;
  const int sr1 = c1i >> 3, ss1 = ((c1i & 7) ^ (sr1 & 7)) << 3;
  const int sd0 = (w << 10);
  const int sd1 = (w << 10) + 512;

  #define STAGE(buf, t0)                                                          \
    do {                                                                           \
      __builtin_amdgcn_global_load_lds((const AS1 void*)(Kh + (size_t)((t0) + sr0) * 64 + ss0), \
                                       (AS3 void*)(ktb + (buf) * 4096 + sd0), 16, 0, 0);  \
      __builtin_amdgcn_global_load_lds((const AS1 void*)(Kh + (size_t)((t0) + sr1) * 64 + ss1), \
                                       (AS3 void*)(ktb + (buf) * 4096 + sd1), 16, 0, 0);  \
      __builtin_amdgcn_global_load_lds((const AS1 void*)(Vh + (size_t)sr0 * 2048 + (t0) + ss0), \
                                       (AS3 void*)(vtb + (buf) * 4096 + sd0), 16, 0, 0);  \
      __builtin_amdgcn_global_load_lds((const AS1 void*)(Vh + (size_t)sr1 * 2048 + (t0) + ss1), \
                                       (AS3 void*)(vtb + (buf) * 4096 + sd1), 16, 0, 0);  \
    } while (0)

  STAGE(0, 0);
  __syncthreads();

  const int xq = ql & 7;
  int cur = 0;
  for (int t0 = 0; t0 < 2048; t0 += 64) {
    if (t0 + 64 < 2048) STAGE(cur ^ 1, t0 + 64);

    const u16* kb = ktb + cur * 4096;
    const u16* vb = vtb + cur * 4096;

    // S^T = K Q^T : s0 -> tk 0-31, s1 -> tk 32-63
    f16v s0 = {}, s1 = {};
    #pragma unroll
    for (int ks = 0; ks < 4; ++ks) {
      bf8 kf0 = *(const bf8*)(kb + (ql << 6) + ((((ks << 1) + hi) ^ xq) << 3));
      bf8 kf1 = *(const bf8*)(kb + ((32 + ql) << 6) + ((((ks << 1) + hi) ^ xq) << 3));
      __builtin_amdgcn_s_setprio(1);
      s0 = __builtin_amdgcn_mfma_f32_32x32x16_bf16(kf0, qf[ks], s0, 0, 0, 0);
      s1 = __builtin_amdgcn_mfma_f32_32x32x16_bf16(kf1, qf[ks], s1, 0, 0, 0);
      __builtin_amdgcn_s_setprio(0);
    }

    bf8 vf0[4], vf1[4];
    #pragma unroll
    for (int ks = 0; ks < 4; ++ks) {
      vf0[ks] = *(const bf8*)(vb + (ql << 6) + ((((ks << 1) + hi) ^ xq) << 3));
      vf1[ks] = *(const bf8*)(vb + ((32 + ql) << 6) + ((((ks << 1) + hi) ^ xq) << 3));
    }

    float rs = 0.f;

    // ---- half 0: softmax+pack s0, PV ks=0,1 ----
    {
      unsigned wpk[8];
      #pragma unroll
      for (int i = 0; i < 8; ++i) {
        float e0 = __builtin_amdgcn_exp2f(s0[2 * i]);
        float e1 = __builtin_amdgcn_exp2f(s0[2 * i + 1]);
        rs += e0 + e1;
        wpk[i] = cvtpk(e0, e1);
      }
      swap32(wpk[0], wpk[2]); swap32(wpk[1], wpk[3]);
      swap32(wpk[4], wpk[6]); swap32(wpk[5], wpk[7]);
      bf8 pf0 = __builtin_bit_cast(bf8, make_uint4(wpk[0], wpk[1], wpk[2], wpk[3]));
      bf8 pf1 = __builtin_bit_cast(bf8, make_uint4(wpk[4], wpk[5], wpk[6], wpk[7]));
      __builtin_amdgcn_s_setprio(1);
      o0 = __builtin_amdgcn_mfma_f32_32x32x16_bf16(vf0[0], pf0, o0, 0, 0, 0);
      o1 = __builtin_amdgcn_mfma_f32_32x32x16_bf16(vf1[0], pf0, o1, 0, 0, 0);
      o0 = __builtin_amdgcn_mfma_f32_32x32x16_bf16(vf0[1], pf1, o0, 0, 0, 0);
      o1 = __builtin_amdgcn_mfma_f32_32x32x16_bf16(vf1[1], pf1, o1, 0, 0, 0);
      __builtin_amdgcn_s_setprio(0);
    }

    // ---- half 1: softmax+pack s1, PV ks=2,3 ----
    {
      unsigned wpk[8];
      #pragma unroll
      for (int i = 0; i < 8; ++i) {
        float e0 = __builtin_amdgcn_exp2f(s1[2 * i]);
        float e1 = __builtin_amdgcn_exp2f(s1[2 * i + 1]);
        rs += e0 + e1;
        wpk[i] = cvtpk(e0, e1);
      }
      swap32(wpk[0], wpk[2]); swap32(wpk[1], wpk[3]);
      swap32(wpk[4], wpk[6]); swap32(wpk[5], wpk[7]);
      bf8 pf2 = __builtin_bit_cast(bf8, make_uint4(wpk[0], wpk[1], wpk[2], wpk[3]));
      bf8 pf3 = __builtin_bit_cast(bf8, make_uint4(wpk[4], wpk[5], wpk[6], wpk[7]));
      __builtin_amdgcn_s_setprio(1);
      o0 = __builtin_amdgcn_mfma_f32_32x32x16_bf16(vf0[2], pf2, o0, 0, 0, 0);
      o1 = __builtin_amdgcn_mfma_f32_32x32x16_bf16(vf1[2], pf2, o1, 0, 0, 0);
      o0 = __builtin_amdgcn_mfma_f32_32x32x16_bf16(vf0[3], pf3, o0, 0, 0, 0);
      o1 = __builtin_amdgcn_mfma_f32_32x32x16_bf16(vf1[3], pf3, o1, 0, 0, 0);
      __builtin_amdgcn_s_setprio(0);
    }

    lrun += rs;
    __syncthreads();
    cur ^= 1;
  }
  #undef STAGE

  const float linv = 1.f / (lrun + __shfl_xor(lrun, 32));

  __syncthreads();
  u16* const ot = pool;
  const int orow = w * 32 + ql;
  #pragma unroll
  for (int c = 0; c < 2; ++c) {
    const f16v& o = c ? o1 : o0;
    #pragma unroll
    for (int g = 0; g < 4; ++g) {
      uint2 pk;
      pk.x = cvtpk(o[4 * g + 0] * linv, o[4 * g + 1] * linv);
      pk.y = cvtpk(o[4 * g + 2] * linv, o[4 * g + 3] * linv);
      *(uint2*)(ot + orow * 72 + 32 * c + 8 * g + 4 * hi) = pk;
    }
  }
  __syncthreads();

  const int b = bh >> 4, h = bh & 15;
  const int row = tid >> 1, seg = tid & 1;
  const u16* src = ot + row * 72 + seg * 32;
  u16* dst = Ob + ((size_t)(b * 2048 + tq0 + row) * 16 + h) * 64 + seg * 32;
  #pragma unroll
  for (int kk = 0; kk < 4; ++kk)
    *(uint4*)(dst + 8 * kk) = *(const uint4*)(src + 8 * kk);
}

// ---------------- host launch ----------------
extern "C" void kernel_launch(void* const* d_in, const int* in_sizes, int n_in,
                              void* d_out, int out_size, void* d_ws, size_t ws_size,
                              hipStream_t stream) {
  (void)in_sizes; (void)n_in; (void)out_size; (void)ws_size;
  const float* k_in = (const float*)d_in[0];
  const float* q_in = (const float*)d_in[1];
  const float* v_in = (const float*)d_in[2];
  const float* Wk = (const float*)d_in[3]; const float* bk = (const float*)d_in[4];
  const float* Wq = (const float*)d_in[5]; const float* bq = (const float*)d_in[6];
  const float* Wv = (const float*)d_in[7]; const float* bv = (const float*)d_in[8];
  const float* Wo = (const float*)d_in[9]; const float* bo = (const float*)d_in[10];
  float* out = (float*)d_out;

  char* ws = (char*)d_ws;
  const size_t SZ_ACT = (size_t)8192 * 1024 * 2;   // 16 MB bf16
  const size_t SZ_W   = (size_t)1024 * 1024 * 2;   // 2 MB bf16
  u16* Oc  = (u16*)(ws);
  u16* Qp  = (u16*)(ws + 1 * SZ_ACT);
  u16* Kp  = (u16*)(ws + 2 * SZ_ACT);
  u16* Vt  = (u16*)(ws + 3 * SZ_ACT);               // [B,H,CH,T]
  u16* Wqb = (u16*)(ws + 4 * SZ_ACT);
  u16* Wkb = (u16*)(ws + 4 * SZ_ACT + SZ_W);
  u16* Wvb = (u16*)(ws + 4 * SZ_ACT + 2 * SZ_W);
  u16* Wob = (u16*)(ws + 4 * SZ_ACT + 3 * SZ_W);

  // weights: one fused convert (outputs contiguous Wq|Wk|Wv|Wo)
  cvt4_kernel<<<4096, 256, 0, stream>>>(Wq, Wk, Wv, Wo, Wqb);

  const float c0 = 0.125f * 1.4426950408889634f;    // softmax scale * log2(e)

  // merged projections: Q (pre-scaled), K -> [B,H,T,CH]; V -> [B,H,CH,T]
  proj_qkv<<<1536, 256, 0, stream>>>(q_in, k_in, v_in, Wqb, Wkb, Wvb,
                                     bq, bk, bv, Qp, Kp, Vt, c0);

  // flash attention -> [B,T,C] bf16
  attn_kernel<<<1024, 256, 0, stream>>>(Qp, Kp, Vt, Oc);

  // output projection -> fp32
  gemm_out<<<512, 256, 0, stream>>>(Oc, Wob, bo, out);
}

// Round 10
// 182.582 us; speedup vs baseline: 1.4542x; 1.4542x over previous
//
#include <hip/hip_runtime.h>

// ---------------------------------------------------------------------------
// Attention block: out = (softmax((q Wq^T+bq)(k Wk^T+bk)^T / 8) (v Wv^T+bv)) Wo^T + bo
// B=4 T=2048 C=1024 H=16 CH=64.  Internal compute bf16 MFMA + f32 accum.
// R9: revert R8 (weights back to glds LDS dbuf = R7 GEMMs).  Attn rewritten
//     to 3-buffer counted-vmcnt pipeline: raw s_barrier + s_waitcnt vmcnt(4)
//     (never 0 in main loop) so staging loads stay in flight across barriers.
// ---------------------------------------------------------------------------

typedef short bf8 __attribute__((ext_vector_type(8)));      // 8 bf16 (4 VGPRs)
typedef float f4 __attribute__((ext_vector_type(4)));
typedef float f16v __attribute__((ext_vector_type(16)));
typedef unsigned short u16;

#define AS1 __attribute__((address_space(1)))
#define AS3 __attribute__((address_space(3)))

__device__ __forceinline__ u16 f2b(float f) {
  unsigned u = __builtin_bit_cast(unsigned, f);
  u += 0x7FFFu + ((u >> 16) & 1u);          // RNE
  return (u16)(u >> 16);
}

__device__ __forceinline__ unsigned cvtpk(float lo, float hi) {
  unsigned r;
  asm("v_cvt_pk_bf16_f32 %0, %1, %2" : "=v"(r) : "v"(lo), "v"(hi));
  return r;
}

__device__ __forceinline__ void swap32(unsigned& a, unsigned& b) {
  asm("v_permlane32_swap_b32 %0, %1" : "+v"(a), "+v"(b));
}

// ---------------- fused weight converts (4 x 1024x1024 fp32 -> bf16) --------
__global__ void cvt4_kernel(const float* __restrict__ a, const float* __restrict__ b,
                            const float* __restrict__ c, const float* __restrict__ d,
                            u16* __restrict__ out) {
  int i = blockIdx.x * blockDim.x + threadIdx.x;     // i in [0, 4*2^18)
  const int sel = i >> 18, off = i & 0x3FFFF;
  const float* src = sel == 0 ? a : sel == 1 ? b : sel == 2 ? c : d;
  float4 f = ((const float4*)src)[off];
  ushort4 o;
  o.x = f2b(f.x); o.y = f2b(f.y); o.z = f2b(f.z); o.w = f2b(f.w);
  ((ushort4*)out)[i] = o;
}

// ---------------- epilogues ----------------
template<int MODE>
__device__ __forceinline__ void gemm_epilogue(
    f4 (&acc)[4][4], const float* __restrict__ bias, void* __restrict__ Cout,
    int N, float scale, int m0, int n0, int wm, int wn, int lr, int lg)
{
  if (MODE == 0) {
    float bv[4];
    #pragma unroll
    for (int j = 0; j < 4; ++j) bv[j] = bias[n0 + wn + j * 16 + lr];
    float* C = (float*)Cout;
    #pragma unroll
    for (int i = 0; i < 4; ++i)
      #pragma unroll
      for (int j = 0; j < 4; ++j) {
        const int col = n0 + wn + j * 16 + lr;
        #pragma unroll
        for (int r = 0; r < 4; ++r) {
          const int row = m0 + wm + i * 16 + lg * 4 + r;
          C[(size_t)row * N + col] = acc[i][j][r] + bv[j];
        }
      }
  } else if (MODE == 1) {
    float bv[4];
    #pragma unroll
    for (int j = 0; j < 4; ++j) bv[j] = bias[n0 + wn + j * 16 + lr];
    u16* C = (u16*)Cout;
    #pragma unroll
    for (int i = 0; i < 4; ++i)
      #pragma unroll
      for (int j = 0; j < 4; ++j) {
        const int col = n0 + wn + j * 16 + lr;     // n = h*64+ch
        const int h = col >> 6, ch = col & 63;
        #pragma unroll
        for (int r = 0; r < 4; ++r) {
          const int row = m0 + wm + i * 16 + lg * 4 + r;  // m = b*2048+t
          const int b = row >> 11, t = row & 2047;
          C[((size_t)(b * 16 + h) * 2048 + t) * 64 + ch] = f2b((acc[i][j][r] + bv[j]) * scale);
        }
      }
  } else {
    u16* C = (u16*)Cout;
    #pragma unroll
    for (int i = 0; i < 4; ++i)
      #pragma unroll
      for (int r = 0; r < 4; ++r) {
        const int nch = m0 + wm + i * 16 + lg * 4 + r;
        const float br = bias[nch];
        const int h = nch >> 6, ch = nch & 63;
        #pragma unroll
        for (int j = 0; j < 4; ++j) {
          const int tok = n0 + wn + j * 16 + lr;
          const int b = tok >> 11, t = tok & 2047;
          C[((size_t)((b * 16 + h) * 64 + ch) << 11) + t] = f2b(acc[i][j][r] + br);
        }
      }
  }
}

// ---------------- pipelined fp-act GEMM body (R7) ----------------
// ACTB=0: A = fp32 act (rows m), B = bf16 weights.  ACTB=1: A = weights, B = act.
// LDS: actT/wT each 2 x 8192 u16 (double-buffered), XOR-swizzled layout:
// slot (row, x) holds data chunk x^(row&7); one __syncthreads per K-step.
template<int MODE, int ACTB>
__device__ __forceinline__ void gemm_fp_body(
    u16* __restrict__ actT, u16* __restrict__ wT,
    const float* __restrict__ act, const u16* __restrict__ Wt,
    const float* __restrict__ bias, void* __restrict__ Cout,
    int N, int K, float scale, int m0, int n0)
{
  const int tid = threadIdx.x, lane = tid & 63, w = tid >> 6;
  const int wm = (w >> 1) << 6, wn = (w & 1) << 6;
  const int lr = lane & 15, lg = lane >> 4;
  const int arow0 = (ACTB ? n0 : m0);
  const int wrow0 = (ACTB ? m0 : n0);

  f4 acc[4][4] = {};
  float4 ta[8];

  // prologue: act(0)->regs->LDS buf0; glds w(0)->buf0; act(1)->regs
  #pragma unroll
  for (int q = 0; q < 4; ++q) {
    const int c = (w << 8) + (q << 6) + lane;
    const int row = c >> 3, col = (c & 7) << 3;
    const float* s = act + (size_t)(arow0 + row) * K + col;
    ta[2 * q] = *(const float4*)s; ta[2 * q + 1] = *(const float4*)(s + 4);
  }
  #pragma unroll
  for (int q = 0; q < 4; ++q) {
    const int c = (w << 8) + (q << 6) + lane;
    const int row = c >> 3, sw = ((c & 7) ^ (row & 7)) << 3;
    __builtin_amdgcn_global_load_lds(
        (const AS1 void*)(Wt + (size_t)(wrow0 + row) * K + sw),
        (AS3 void*)(wT + (((w << 2) + q) << 9)), 16, 0, 0);
  }
  #pragma unroll
  for (int q = 0; q < 4; ++q) {
    const int c = (w << 8) + (q << 6) + lane;
    const int row = c >> 3;
    uint4 pk;
    pk.x = cvtpk(ta[2 * q].x, ta[2 * q].y);
    pk.y = cvtpk(ta[2 * q].z, ta[2 * q].w);
    pk.z = cvtpk(ta[2 * q + 1].x, ta[2 * q + 1].y);
    pk.w = cvtpk(ta[2 * q + 1].z, ta[2 * q + 1].w);
    *(uint4*)(actT + (row << 6) + (((c & 7) ^ (row & 7)) << 3)) = pk;
  }
  #pragma unroll
  for (int q = 0; q < 4; ++q) {
    const int c = (w << 8) + (q << 6) + lane;
    const int row = c >> 3, col = (c & 7) << 3;
    const float* s = act + (size_t)(arow0 + row) * K + 64 + col;
    ta[2 * q] = *(const float4*)s; ta[2 * q + 1] = *(const float4*)(s + 4);
  }
  __syncthreads();

  const int NKT = K >> 6;
  for (int kt = 0; kt < NKT; ++kt) {
    const int cur = kt & 1;
    const u16* aC = actT + (cur << 13);
    const u16* wC = wT + (cur << 13);
    if (kt + 1 < NKT) {
      u16* aN = actT + ((cur ^ 1) << 13);
      u16* wN = wT + ((cur ^ 1) << 13);
      const int k1 = (kt + 1) << 6;
      #pragma unroll
      for (int q = 0; q < 4; ++q) {
        const int c = (w << 8) + (q << 6) + lane;
        const int row = c >> 3, sw = ((c & 7) ^ (row & 7)) << 3;
        __builtin_amdgcn_global_load_lds(
            (const AS1 void*)(Wt + (size_t)(wrow0 + row) * K + k1 + sw),
            (AS3 void*)(wN + (((w << 2) + q) << 9)), 16, 0, 0);
      }
      #pragma unroll
      for (int q = 0; q < 4; ++q) {
        const int c = (w << 8) + (q << 6) + lane;
        const int row = c >> 3;
        uint4 pk;
        pk.x = cvtpk(ta[2 * q].x, ta[2 * q].y);
        pk.y = cvtpk(ta[2 * q].z, ta[2 * q].w);
        pk.z = cvtpk(ta[2 * q + 1].x, ta[2 * q + 1].y);
        pk.w = cvtpk(ta[2 * q + 1].z, ta[2 * q + 1].w);
        *(uint4*)(aN + (row << 6) + (((c & 7) ^ (row & 7)) << 3)) = pk;
      }
      if (kt + 2 < NKT) {
        const int k2 = (kt + 2) << 6;
        #pragma unroll
        for (int q = 0; q < 4; ++q) {
          const int c = (w << 8) + (q << 6) + lane;
          const int row = c >> 3, col = (c & 7) << 3;
          const float* s = act + (size_t)(arow0 + row) * K + k2 + col;
          ta[2 * q] = *(const float4*)s; ta[2 * q + 1] = *(const float4*)(s + 4);
        }
      }
    }
    #pragma unroll
    for (int ks = 0; ks < 2; ++ks) {
      bf8 af[4], bfr[4];
      #pragma unroll
      for (int i = 0; i < 4; ++i) {
        const int ra = wm + i * 16 + lr;
        const int rb = wn + i * 16 + lr;
        const u16* aSrc = ACTB ? wC : aC;
        const u16* bSrc = ACTB ? aC : wC;
        af[i]  = *(const bf8*)(aSrc + (ra << 6) + ((((ks << 2) + lg) ^ (ra & 7)) << 3));
        bfr[i] = *(const bf8*)(bSrc + (rb << 6) + ((((ks << 2) + lg) ^ (rb & 7)) << 3));
      }
      __builtin_amdgcn_s_setprio(1);
      #pragma unroll
      for (int i = 0; i < 4; ++i)
        #pragma unroll
        for (int j = 0; j < 4; ++j)
          acc[i][j] = __builtin_amdgcn_mfma_f32_16x16x32_bf16(af[i], bfr[j], acc[i][j], 0, 0, 0);
      __builtin_amdgcn_s_setprio(0);
    }
    __syncthreads();
  }

  gemm_epilogue<MODE>(acc, bias, Cout, N, scale, m0, n0, wm, wn, lr, lg);
}

// ---------------- merged QKV projection dispatch (1536 blocks) ----------------
__global__ __launch_bounds__(256, 2)
void proj_qkv(const float* __restrict__ q_in, const float* __restrict__ k_in,
              const float* __restrict__ v_in,
              const u16* __restrict__ Wq, const u16* __restrict__ Wk,
              const u16* __restrict__ Wv,
              const float* __restrict__ bq, const float* __restrict__ bk,
              const float* __restrict__ bv,
              u16* __restrict__ Qp, u16* __restrict__ Kp, u16* __restrict__ Vt,
              float qscale)
{
  __shared__ __align__(16) u16 pool[32768];     // 64 KB: actT[2][8192] | wT[2][8192]
  u16* const actT = pool;
  u16* const wT   = pool + 16384;

  const int cpx = gridDim.x >> 3;
  const int bid = (blockIdx.x & 7) * cpx + (blockIdx.x >> 3);
  const int which = bid >> 9, sub = bid & 511;

  if (which < 2) {
    gemm_fp_body<1, 0>(actT, wT,
                       which ? k_in : q_in,
                       which ? Wk : Wq,
                       which ? bk : bq,
                       which ? (void*)Kp : (void*)Qp,
                       1024, 1024, which ? 1.f : qscale,
                       (sub >> 3) << 7, (sub & 7) << 7);
  } else {
    gemm_fp_body<2, 1>(actT, wT, v_in, Wv, bv, (void*)Vt,
                       8192, 1024, 1.f, (sub & 7) << 7, (sub >> 3) << 7);
  }
}

// ---------------- output projection (all-bf16, pipelined, R7) ----------------
__global__ __launch_bounds__(256, 2)
void gemm_out(const u16* __restrict__ A, const u16* __restrict__ B,
              const float* __restrict__ bias, float* __restrict__ C)
{
  __shared__ __align__(16) u16 pool[32768];     // aT[2][8192] | bT[2][8192]
  u16* const aT = pool;
  u16* const bT = pool + 16384;

  const int cpx = gridDim.x >> 3;
  const int bid = (blockIdx.x & 7) * cpx + (blockIdx.x >> 3);
  const int m0 = (bid >> 3) << 7, n0 = (bid & 7) << 7;
  const int tid = threadIdx.x, lane = tid & 63, w = tid >> 6;
  const int wm = (w >> 1) << 6, wn = (w & 1) << 6;
  const int lr = lane & 15, lg = lane >> 4;
  const int K = 1024;

  f4 acc[4][4] = {};

  #pragma unroll
  for (int q = 0; q < 4; ++q) {
    const int c = (w << 8) + (q << 6) + lane;
    const int row = c >> 3, sw = ((c & 7) ^ (row & 7)) << 3;
    __builtin_amdgcn_global_load_lds(
        (const AS1 void*)(A + (size_t)(m0 + row) * K + sw),
        (AS3 void*)(aT + (((w << 2) + q) << 9)), 16, 0, 0);
    __builtin_amdgcn_global_load_lds(
        (const AS1 void*)(B + (size_t)(n0 + row) * K + sw),
        (AS3 void*)(bT + (((w << 2) + q) << 9)), 16, 0, 0);
  }
  __syncthreads();

  for (int kt = 0; kt < 16; ++kt) {
    const int cur = kt & 1;
    const u16* aC = aT + (cur << 13);
    const u16* bC = bT + (cur << 13);
    if (kt + 1 < 16) {
      u16* aN = aT + ((cur ^ 1) << 13);
      u16* bN = bT + ((cur ^ 1) << 13);
      const int k1 = (kt + 1) << 6;
      #pragma unroll
      for (int q = 0; q < 4; ++q) {
        const int c = (w << 8) + (q << 6) + lane;
        const int row = c >> 3, sw = ((c & 7) ^ (row & 7)) << 3;
        __builtin_amdgcn_global_load_lds(
            (const AS1 void*)(A + (size_t)(m0 + row) * K + k1 + sw),
            (AS3 void*)(aN + (((w << 2) + q) << 9)), 16, 0, 0);
        __builtin_amdgcn_global_load_lds(
            (const AS1 void*)(B + (size_t)(n0 + row) * K + k1 + sw),
            (AS3 void*)(bN + (((w << 2) + q) << 9)), 16, 0, 0);
      }
    }
    #pragma unroll
    for (int ks = 0; ks < 2; ++ks) {
      bf8 af[4], bfr[4];
      #pragma unroll
      for (int i = 0; i < 4; ++i) {
        const int ra = wm + i * 16 + lr;
        const int rb = wn + i * 16 + lr;
        af[i]  = *(const bf8*)(aC + (ra << 6) + ((((ks << 2) + lg) ^ (ra & 7)) << 3));
        bfr[i] = *(const bf8*)(bC + (rb << 6) + ((((ks << 2) + lg) ^ (rb & 7)) << 3));
      }
      __builtin_amdgcn_s_setprio(1);
      #pragma unroll
      for (int i = 0; i < 4; ++i)
        #pragma unroll
        for (int j = 0; j < 4; ++j)
          acc[i][j] = __builtin_amdgcn_mfma_f32_16x16x32_bf16(af[i], bfr[j], acc[i][j], 0, 0, 0);
      __builtin_amdgcn_s_setprio(0);
    }
    __syncthreads();
  }

  gemm_epilogue<0>(acc, bias, (void*)C, 1024, 1.f, m0, n0, wm, wn, lr, lg);
}

// ---------------- flash attention: 3-buffer counted-vmcnt pipeline -----------
// grid 1024 (XCD-mapped), 256 threads = 4 waves x 32 q.
// Q (pre-scaled by 0.125*log2e), K in [B,H,T,CH]; V^T in [B,H,CH,T]; O in [B,T,C].
// Per tile per thread: 4 global_load_lds (2 K + 2 V). 2-ahead staging; at the
// top-of-iteration barrier we wait vmcnt(4) (newest stage stays in flight).
__global__ __launch_bounds__(256, 3)
void attn_kernel(const u16* __restrict__ Qp, const u16* __restrict__ Kp,
                 const u16* __restrict__ VT, u16* __restrict__ Ob)
{
  __shared__ __align__(16) u16 pool[24576];     // 48 KB: kt[3][4096] | vt[3][4096]; reused as ot[128][72]
  u16* const ktb = pool;
  u16* const vtb = pool + 12288;

  const int flat = blockIdx.x;
  const int xcd = flat & 7, idx = flat >> 3;
  const int bh = (xcd << 3) + (idx >> 4);
  const int tq0 = (idx & 15) << 7;

  const int tid = threadIdx.x, lane = tid & 63, w = tid >> 6;
  const int ql = lane & 31, hi = lane >> 5;
  const size_t hoff = (size_t)bh * (2048 * 64);
  const u16* Kh = Kp + hoff;
  const u16* Vh = VT + hoff;

  bf8 qf[4];
  {
    const u16* qp_ = Qp + hoff + (size_t)(tq0 + w * 32 + ql) * 64 + hi * 8;
    #pragma unroll
    for (int ks = 0; ks < 4; ++ks) qf[ks] = *(const bf8*)(qp_ + 16 * ks);
  }

  f16v o0 = {}, o1 = {};
  float lrun = 0.f;

  const int c0i = (w << 7) + lane;
  const int c1i = c0i + 64;
  const int sr0 = c0i >> 3, ss0 = ((c0i & 7) ^ (sr0 & 7)) << 3;
  const int sr1 = c1i >> 3, ss1 = ((c1i & 7) ^ (sr1 & 7)) << 3;
  const int sd0 = (w << 10);
  const int sd1 = (w << 10) + 512;

  #define STAGE(buf, t0)                                                          \
    do {                                                                           \
      __builtin_amdgcn_global_load_lds((const AS1 void*)(Kh + (size_t)((t0) + sr0) * 64 + ss0), \
                                       (AS3 void*)(ktb + (buf) * 4096 + sd0), 16, 0, 0);  \
      __builtin_amdgcn_global_load_lds((const AS1 void*)(Kh + (size_t)((t0) + sr1) * 64 + ss1), \
                                       (AS3 void*)(ktb + (buf) * 4096 + sd1), 16, 0, 0);  \
      __builtin_amdgcn_global_load_lds((const AS1 void*)(Vh + (size_t)sr0 * 2048 + (t0) + ss0), \
                                       (AS3 void*)(vtb + (buf) * 4096 + sd0), 16, 0, 0);  \
      __builtin_amdgcn_global_load_lds((const AS1 void*)(Vh + (size_t)sr1 * 2048 + (t0) + ss1), \
                                       (AS3 void*)(vtb + (buf) * 4096 + sd1), 16, 0, 0);  \
    } while (0)

  STAGE(0, 0);
  STAGE(1, 64);

  const int xq = ql & 7;
  int bc = 0;                         // buffer holding the current tile
  for (int it = 0; it < 32; ++it) {
    // stage(it) must be complete; stage(it+1) may stay in flight.
    if (it < 31) asm volatile("s_waitcnt vmcnt(4)" ::: "memory");
    else         asm volatile("s_waitcnt vmcnt(0)" ::: "memory");
    __builtin_amdgcn_s_barrier();
    __builtin_amdgcn_sched_barrier(0);

    // stage tile it+2 into buffer (it+2)%3 == (it-1)%3 (read finished by all
    // waves before the barrier above).
    if (it + 2 < 32) {
      const int bs = bc ? bc - 1 : 2;
      STAGE(bs, (it + 2) << 6);
    }

    const u16* kb = ktb + bc * 4096;
    const u16* vb = vtb + bc * 4096;

    // S^T = K Q^T : s0 -> tk 0-31, s1 -> tk 32-63
    f16v s0 = {}, s1 = {};
    #pragma unroll
    for (int ks = 0; ks < 4; ++ks) {
      bf8 kf0 = *(const bf8*)(kb + (ql << 6) + ((((ks << 1) + hi) ^ xq) << 3));
      bf8 kf1 = *(const bf8*)(kb + ((32 + ql) << 6) + ((((ks << 1) + hi) ^ xq) << 3));
      __builtin_amdgcn_s_setprio(1);
      s0 = __builtin_amdgcn_mfma_f32_32x32x16_bf16(kf0, qf[ks], s0, 0, 0, 0);
      s1 = __builtin_amdgcn_mfma_f32_32x32x16_bf16(kf1, qf[ks], s1, 0, 0, 0);
      __builtin_amdgcn_s_setprio(0);
    }

    bf8 vf0[4], vf1[4];
    #pragma unroll
    for (int ks = 0; ks < 4; ++ks) {
      vf0[ks] = *(const bf8*)(vb + (ql << 6) + ((((ks << 1) + hi) ^ xq) << 3));
      vf1[ks] = *(const bf8*)(vb + ((32 + ql) << 6) + ((((ks << 1) + hi) ^ xq) << 3));
    }

    float rs = 0.f;

    // ---- half 0: softmax+pack s0, PV ks=0,1 ----
    {
      unsigned wpk[8];
      #pragma unroll
      for (int i = 0; i < 8; ++i) {
        float e0 = __builtin_amdgcn_exp2f(s0[2 * i]);
        float e1 = __builtin_amdgcn_exp2f(s0[2 * i + 1]);
        rs += e0 + e1;
        wpk[i] = cvtpk(e0, e1);
      }
      swap32(wpk[0], wpk[2]); swap32(wpk[1], wpk[3]);
      swap32(wpk[4], wpk[6]); swap32(wpk[5], wpk[7]);
      bf8 pf0 = __builtin_bit_cast(bf8, make_uint4(wpk[0], wpk[1], wpk[2], wpk[3]));
      bf8 pf1 = __builtin_bit_cast(bf8, make_uint4(wpk[4], wpk[5], wpk[6], wpk[7]));
      __builtin_amdgcn_s_setprio(1);
      o0 = __builtin_amdgcn_mfma_f32_32x32x16_bf16(vf0[0], pf0, o0, 0, 0, 0);
      o1 = __builtin_amdgcn_mfma_f32_32x32x16_bf16(vf1[0], pf0, o1, 0, 0, 0);
      o0 = __builtin_amdgcn_mfma_f32_32x32x16_bf16(vf0[1], pf1, o0, 0, 0, 0);
      o1 = __builtin_amdgcn_mfma_f32_32x32x16_bf16(vf1[1], pf1, o1, 0, 0, 0);
      __builtin_amdgcn_s_setprio(0);
    }

    // ---- half 1: softmax+pack s1, PV ks=2,3 ----
    {
      unsigned wpk[8];
      #pragma unroll
      for (int i = 0; i < 8; ++i) {
        float e0 = __builtin_amdgcn_exp2f(s1[2 * i]);
        float e1 = __builtin_amdgcn_exp2f(s1[2 * i + 1]);
        rs += e0 + e1;
        wpk[i] = cvtpk(e0, e1);
      }
      swap32(wpk[0], wpk[2]); swap32(wpk[1], wpk[3]);
      swap32(wpk[4], wpk[6]); swap32(wpk[5], wpk[7]);
      bf8 pf2 = __builtin_bit_cast(bf8, make_uint4(wpk[0], wpk[1], wpk[2], wpk[3]));
      bf8 pf3 = __builtin_bit_cast(bf8, make_uint4(wpk[4], wpk[5], wpk[6], wpk[7]));
      __builtin_amdgcn_s_setprio(1);
      o0 = __builtin_amdgcn_mfma_f32_32x32x16_bf16(vf0[2], pf2, o0, 0, 0, 0);
      o1 = __builtin_amdgcn_mfma_f32_32x32x16_bf16(vf1[2], pf2, o1, 0, 0, 0);
      o0 = __builtin_amdgcn_mfma_f32_32x32x16_bf16(vf0[3], pf3, o0, 0, 0, 0);
      o1 = __builtin_amdgcn_mfma_f32_32x32x16_bf16(vf1[3], pf3, o1, 0, 0, 0);
      __builtin_amdgcn_s_setprio(0);
    }

    lrun += rs;
    bc = bc + 1 < 3 ? bc + 1 : 0;
  }
  #undef STAGE

  const float linv = 1.f / (lrun + __shfl_xor(lrun, 32));

  __syncthreads();                    // protects pool reuse (ot) vs last tile reads
  u16* const ot = pool;
  const int orow = w * 32 + ql;
  #pragma unroll
  for (int c = 0; c < 2; ++c) {
    const f16v& o = c ? o1 : o0;
    #pragma unroll
    for (int g = 0; g < 4; ++g) {
      uint2 pk;
      pk.x = cvtpk(o[4 * g + 0] * linv, o[4 * g + 1] * linv);
      pk.y = cvtpk(o[4 * g + 2] * linv, o[4 * g + 3] * linv);
      *(uint2*)(ot + orow * 72 + 32 * c + 8 * g + 4 * hi) = pk;
    }
  }
  __syncthreads();

  const int b = bh >> 4, h = bh & 15;
  const int row = tid >> 1, seg = tid & 1;
  const u16* src = ot + row * 72 + seg * 32;
  u16* dst = Ob + ((size_t)(b * 2048 + tq0 + row) * 16 + h) * 64 + seg * 32;
  #pragma unroll
  for (int kk = 0; kk < 4; ++kk)
    *(uint4*)(dst + 8 * kk) = *(const uint4*)(src + 8 * kk);
}

// ---------------- host launch ----------------
extern "C" void kernel_launch(void* const* d_in, const int* in_sizes, int n_in,
                              void* d_out, int out_size, void* d_ws, size_t ws_size,
                              hipStream_t stream) {
  (void)in_sizes; (void)n_in; (void)out_size; (void)ws_size;
  const float* k_in = (const float*)d_in[0];
  const float* q_in = (const float*)d_in[1];
  const float* v_in = (const float*)d_in[2];
  const float* Wk = (const float*)d_in[3]; const float* bk = (const float*)d_in[4];
  const float* Wq = (const float*)d_in[5]; const float* bq = (const float*)d_in[6];
  const float* Wv = (const float*)d_in[7]; const float* bv = (const float*)d_in[8];
  const float* Wo = (const float*)d_in[9]; const float* bo = (const float*)d_in[10];
  float* out = (float*)d_out;

  char* ws = (char*)d_ws;
  const size_t SZ_ACT = (size_t)8192 * 1024 * 2;   // 16 MB bf16
  const size_t SZ_W   = (size_t)1024 * 1024 * 2;   // 2 MB bf16
  u16* Oc  = (u16*)(ws);
  u16* Qp  = (u16*)(ws + 1 * SZ_ACT);
  u16* Kp  = (u16*)(ws + 2 * SZ_ACT);
  u16* Vt  = (u16*)(ws + 3 * SZ_ACT);               // [B,H,CH,T]
  u16* Wqb = (u16*)(ws + 4 * SZ_ACT);
  u16* Wkb = (u16*)(ws + 4 * SZ_ACT + SZ_W);
  u16* Wvb = (u16*)(ws + 4 * SZ_ACT + 2 * SZ_W);
  u16* Wob = (u16*)(ws + 4 * SZ_ACT + 3 * SZ_W);

  // weights: one fused convert (outputs contiguous Wq|Wk|Wv|Wo)
  cvt4_kernel<<<4096, 256, 0, stream>>>(Wq, Wk, Wv, Wo, Wqb);

  const float c0 = 0.125f * 1.4426950408889634f;    // softmax scale * log2(e)

  // merged projections: Q (pre-scaled), K -> [B,H,T,CH]; V -> [B,H,CH,T]
  proj_qkv<<<1536, 256, 0, stream>>>(q_in, k_in, v_in, Wqb, Wkb, Wvb,
                                     bq, bk, bv, Qp, Kp, Vt, c0);

  // flash attention -> [B,T,C] bf16
  attn_kernel<<<1024, 256, 0, stream>>>(Qp, Kp, Vt, Oc);

  // output projection -> fp32
  gemm_out<<<512, 256, 0, stream>>>(Oc, Wob, bo, out);
}

// Round 11
// 179.051 us; speedup vs baseline: 1.4829x; 1.0197x over previous
//
#include <hip/hip_runtime.h>

// ---------------------------------------------------------------------------
// Attention block: out = (softmax((q Wq^T+bq)(k Wk^T+bk)^T / 8) (v Wv^T+bv)) Wo^T + bo
// B=4 T=2048 C=1024 H=16 CH=64.  Internal compute bf16 MFMA + f32 accum.
// R10: proj_qkv ported to counted-vmcnt pipeline (raw s_barrier + vmcnt(8),
//      never 0 mid-loop): weight glds and act reg-prefetch stay in flight
//      across barriers.  Attn (R9 3-buffer vmcnt) and gemm_out unchanged.
// ---------------------------------------------------------------------------

typedef short bf8 __attribute__((ext_vector_type(8)));      // 8 bf16 (4 VGPRs)
typedef float f4 __attribute__((ext_vector_type(4)));
typedef float f16v __attribute__((ext_vector_type(16)));
typedef unsigned short u16;

#define AS1 __attribute__((address_space(1)))
#define AS3 __attribute__((address_space(3)))

__device__ __forceinline__ u16 f2b(float f) {
  unsigned u = __builtin_bit_cast(unsigned, f);
  u += 0x7FFFu + ((u >> 16) & 1u);          // RNE
  return (u16)(u >> 16);
}

__device__ __forceinline__ unsigned cvtpk(float lo, float hi) {
  unsigned r;
  asm("v_cvt_pk_bf16_f32 %0, %1, %2" : "=v"(r) : "v"(lo), "v"(hi));
  return r;
}

__device__ __forceinline__ void swap32(unsigned& a, unsigned& b) {
  asm("v_permlane32_swap_b32 %0, %1" : "+v"(a), "+v"(b));
}

// ---------------- fused weight converts (4 x 1024x1024 fp32 -> bf16) --------
__global__ void cvt4_kernel(const float* __restrict__ a, const float* __restrict__ b,
                            const float* __restrict__ c, const float* __restrict__ d,
                            u16* __restrict__ out) {
  int i = blockIdx.x * blockDim.x + threadIdx.x;     // i in [0, 4*2^18)
  const int sel = i >> 18, off = i & 0x3FFFF;
  const float* src = sel == 0 ? a : sel == 1 ? b : sel == 2 ? c : d;
  float4 f = ((const float4*)src)[off];
  ushort4 o;
  o.x = f2b(f.x); o.y = f2b(f.y); o.z = f2b(f.z); o.w = f2b(f.w);
  ((ushort4*)out)[i] = o;
}

// ---------------- epilogues ----------------
template<int MODE>
__device__ __forceinline__ void gemm_epilogue(
    f4 (&acc)[4][4], const float* __restrict__ bias, void* __restrict__ Cout,
    int N, float scale, int m0, int n0, int wm, int wn, int lr, int lg)
{
  if (MODE == 0) {
    float bv[4];
    #pragma unroll
    for (int j = 0; j < 4; ++j) bv[j] = bias[n0 + wn + j * 16 + lr];
    float* C = (float*)Cout;
    #pragma unroll
    for (int i = 0; i < 4; ++i)
      #pragma unroll
      for (int j = 0; j < 4; ++j) {
        const int col = n0 + wn + j * 16 + lr;
        #pragma unroll
        for (int r = 0; r < 4; ++r) {
          const int row = m0 + wm + i * 16 + lg * 4 + r;
          C[(size_t)row * N + col] = acc[i][j][r] + bv[j];
        }
      }
  } else if (MODE == 1) {
    float bv[4];
    #pragma unroll
    for (int j = 0; j < 4; ++j) bv[j] = bias[n0 + wn + j * 16 + lr];
    u16* C = (u16*)Cout;
    #pragma unroll
    for (int i = 0; i < 4; ++i)
      #pragma unroll
      for (int j = 0; j < 4; ++j) {
        const int col = n0 + wn + j * 16 + lr;     // n = h*64+ch
        const int h = col >> 6, ch = col & 63;
        #pragma unroll
        for (int r = 0; r < 4; ++r) {
          const int row = m0 + wm + i * 16 + lg * 4 + r;  // m = b*2048+t
          const int b = row >> 11, t = row & 2047;
          C[((size_t)(b * 16 + h) * 2048 + t) * 64 + ch] = f2b((acc[i][j][r] + bv[j]) * scale);
        }
      }
  } else {
    u16* C = (u16*)Cout;
    #pragma unroll
    for (int i = 0; i < 4; ++i)
      #pragma unroll
      for (int r = 0; r < 4; ++r) {
        const int nch = m0 + wm + i * 16 + lg * 4 + r;
        const float br = bias[nch];
        const int h = nch >> 6, ch = nch & 63;
        #pragma unroll
        for (int j = 0; j < 4; ++j) {
          const int tok = n0 + wn + j * 16 + lr;
          const int b = tok >> 11, t = tok & 2047;
          C[((size_t)((b * 16 + h) * 64 + ch) << 11) + t] = f2b(acc[i][j][r] + br);
        }
      }
  }
}

// ---------------- counted-vmcnt pipelined fp-act GEMM body ----------------
// ACTB=0: A = fp32 act (rows m), B = bf16 weights.  ACTB=1: A = weights, B = act.
// LDS: actT/wT each 2 x 8192 u16, XOR-swizzled (slot (row,x) = chunk x^(row&7)).
// Per K-step: raw s_barrier + counted vmcnt.  Issue order per iter kt:
//   [vmcnt(8 or 0); barrier] -> glds W(kt+1) -> MFMA(kt) -> ds_write act(kt+1)
//   -> global fp32 load act(kt+2) -> lgkmcnt(0).
// vmcnt ledger: at top of kt (kt>=1): outstanding = glds(kt)[4 oldest] +
// actload(kt+1)[8] => vmcnt(8) drains exactly glds(kt).  Last iter: only
// glds left (no act loads issued) => vmcnt(0).
template<int MODE, int ACTB>
__device__ __forceinline__ void gemm_fp_body(
    u16* __restrict__ actT, u16* __restrict__ wT,
    const float* __restrict__ act, const u16* __restrict__ Wt,
    const float* __restrict__ bias, void* __restrict__ Cout,
    int N, int K, float scale, int m0, int n0)
{
  const int tid = threadIdx.x, lane = tid & 63, w = tid >> 6;
  const int wm = (w >> 1) << 6, wn = (w & 1) << 6;
  const int lr = lane & 15, lg = lane >> 4;
  const int arow0 = (ACTB ? n0 : m0);
  const int wrow0 = (ACTB ? m0 : n0);

  f4 acc[4][4] = {};
  float4 ta[8];

  #define W_GLDS(buf, karg)                                                     \
    do {                                                                        \
      const int k_ = (karg);                                                    \
      u16* dst = wT + ((buf) << 13);                                            \
      _Pragma("unroll")                                                         \
      for (int q = 0; q < 4; ++q) {                                             \
        const int c = (w << 8) + (q << 6) + lane;                               \
        const int row = c >> 3, sw = ((c & 7) ^ (row & 7)) << 3;                \
        __builtin_amdgcn_global_load_lds(                                       \
            (const AS1 void*)(Wt + (size_t)(wrow0 + row) * K + k_ + sw),        \
            (AS3 void*)(dst + (((w << 2) + q) << 9)), 16, 0, 0);                \
      }                                                                         \
    } while (0)

  #define ACT_LOAD(karg)                                                        \
    do {                                                                        \
      const int k_ = (karg);                                                    \
      _Pragma("unroll")                                                         \
      for (int q = 0; q < 4; ++q) {                                             \
        const int c = (w << 8) + (q << 6) + lane;                               \
        const int row = c >> 3, col = (c & 7) << 3;                             \
        const float* s = act + (size_t)(arow0 + row) * K + k_ + col;            \
        ta[2 * q] = *(const float4*)s;                                          \
        ta[2 * q + 1] = *(const float4*)(s + 4);                                \
      }                                                                         \
    } while (0)

  #define ACT_WRITE(buf)                                                        \
    do {                                                                        \
      u16* dst = actT + ((buf) << 13);                                          \
      _Pragma("unroll")                                                         \
      for (int q = 0; q < 4; ++q) {                                             \
        const int c = (w << 8) + (q << 6) + lane;                               \
        const int row = c >> 3;                                                 \
        uint4 pk;                                                               \
        pk.x = cvtpk(ta[2 * q].x, ta[2 * q].y);                                 \
        pk.y = cvtpk(ta[2 * q].z, ta[2 * q].w);                                 \
        pk.z = cvtpk(ta[2 * q + 1].x, ta[2 * q + 1].y);                         \
        pk.w = cvtpk(ta[2 * q + 1].z, ta[2 * q + 1].w);                         \
        *(uint4*)(dst + (row << 6) + (((c & 7) ^ (row & 7)) << 3)) = pk;        \
      }                                                                         \
    } while (0)

  // prologue: glds W(0); act(0)->regs->buf0 (drains glds(0) implicitly:
  // glds older than act loads, ACT_WRITE waits act loads); act(1)->regs.
  W_GLDS(0, 0);
  ACT_LOAD(0);
  ACT_WRITE(0);
  ACT_LOAD(64);
  asm volatile("s_waitcnt lgkmcnt(0)" ::: "memory");

  const int NKT = K >> 6;
  for (int kt = 0; kt < NKT; ++kt) {
    const int cur = kt & 1;
    if (kt > 0) {
      if (kt + 1 < NKT) asm volatile("s_waitcnt vmcnt(8)" ::: "memory");
      else              asm volatile("s_waitcnt vmcnt(0)" ::: "memory");
    }
    __builtin_amdgcn_s_barrier();
    __builtin_amdgcn_sched_barrier(0);

    if (kt + 1 < NKT) W_GLDS(cur ^ 1, (kt + 1) << 6);

    const u16* aC = actT + (cur << 13);
    const u16* wC = wT + (cur << 13);
    #pragma unroll
    for (int ks = 0; ks < 2; ++ks) {
      bf8 af[4], bfr[4];
      #pragma unroll
      for (int i = 0; i < 4; ++i) {
        const int ra = wm + i * 16 + lr;
        const int rb = wn + i * 16 + lr;
        const u16* aSrc = ACTB ? wC : aC;
        const u16* bSrc = ACTB ? aC : wC;
        af[i]  = *(const bf8*)(aSrc + (ra << 6) + ((((ks << 2) + lg) ^ (ra & 7)) << 3));
        bfr[i] = *(const bf8*)(bSrc + (rb << 6) + ((((ks << 2) + lg) ^ (rb & 7)) << 3));
      }
      __builtin_amdgcn_s_setprio(1);
      #pragma unroll
      for (int i = 0; i < 4; ++i)
        #pragma unroll
        for (int j = 0; j < 4; ++j)
          acc[i][j] = __builtin_amdgcn_mfma_f32_16x16x32_bf16(af[i], bfr[j], acc[i][j], 0, 0, 0);
      __builtin_amdgcn_s_setprio(0);
    }

    if (kt + 1 < NKT) {
      ACT_WRITE(cur ^ 1);                       // compiler waits act(kt+1) loads (vmcnt(4))
      if (kt + 2 < NKT) ACT_LOAD((kt + 2) << 6);
    }
    asm volatile("s_waitcnt lgkmcnt(0)" ::: "memory");
  }
  #undef W_GLDS
  #undef ACT_LOAD
  #undef ACT_WRITE

  gemm_epilogue<MODE>(acc, bias, Cout, N, scale, m0, n0, wm, wn, lr, lg);
}

// ---------------- merged QKV projection dispatch (1536 blocks) ----------------
__global__ __launch_bounds__(256, 2)
void proj_qkv(const float* __restrict__ q_in, const float* __restrict__ k_in,
              const float* __restrict__ v_in,
              const u16* __restrict__ Wq, const u16* __restrict__ Wk,
              const u16* __restrict__ Wv,
              const float* __restrict__ bq, const float* __restrict__ bk,
              const float* __restrict__ bv,
              u16* __restrict__ Qp, u16* __restrict__ Kp, u16* __restrict__ Vt,
              float qscale)
{
  __shared__ __align__(16) u16 pool[32768];     // 64 KB: actT[2][8192] | wT[2][8192]
  u16* const actT = pool;
  u16* const wT   = pool + 16384;

  const int cpx = gridDim.x >> 3;
  const int bid = (blockIdx.x & 7) * cpx + (blockIdx.x >> 3);
  const int which = bid >> 9, sub = bid & 511;

  if (which < 2) {
    gemm_fp_body<1, 0>(actT, wT,
                       which ? k_in : q_in,
                       which ? Wk : Wq,
                       which ? bk : bq,
                       which ? (void*)Kp : (void*)Qp,
                       1024, 1024, which ? 1.f : qscale,
                       (sub >> 3) << 7, (sub & 7) << 7);
  } else {
    gemm_fp_body<2, 1>(actT, wT, v_in, Wv, bv, (void*)Vt,
                       8192, 1024, 1.f, (sub & 7) << 7, (sub >> 3) << 7);
  }
}

// ---------------- output projection (all-bf16, pipelined, R7) ----------------
__global__ __launch_bounds__(256, 2)
void gemm_out(const u16* __restrict__ A, const u16* __restrict__ B,
              const float* __restrict__ bias, float* __restrict__ C)
{
  __shared__ __align__(16) u16 pool[32768];     // aT[2][8192] | bT[2][8192]
  u16* const aT = pool;
  u16* const bT = pool + 16384;

  const int cpx = gridDim.x >> 3;
  const int bid = (blockIdx.x & 7) * cpx + (blockIdx.x >> 3);
  const int m0 = (bid >> 3) << 7, n0 = (bid & 7) << 7;
  const int tid = threadIdx.x, lane = tid & 63, w = tid >> 6;
  const int wm = (w >> 1) << 6, wn = (w & 1) << 6;
  const int lr = lane & 15, lg = lane >> 4;
  const int K = 1024;

  f4 acc[4][4] = {};

  #pragma unroll
  for (int q = 0; q < 4; ++q) {
    const int c = (w << 8) + (q << 6) + lane;
    const int row = c >> 3, sw = ((c & 7) ^ (row & 7)) << 3;
    __builtin_amdgcn_global_load_lds(
        (const AS1 void*)(A + (size_t)(m0 + row) * K + sw),
        (AS3 void*)(aT + (((w << 2) + q) << 9)), 16, 0, 0);
    __builtin_amdgcn_global_load_lds(
        (const AS1 void*)(B + (size_t)(n0 + row) * K + sw),
        (AS3 void*)(bT + (((w << 2) + q) << 9)), 16, 0, 0);
  }
  __syncthreads();

  for (int kt = 0; kt < 16; ++kt) {
    const int cur = kt & 1;
    const u16* aC = aT + (cur << 13);
    const u16* bC = bT + (cur << 13);
    if (kt + 1 < 16) {
      u16* aN = aT + ((cur ^ 1) << 13);
      u16* bN = bT + ((cur ^ 1) << 13);
      const int k1 = (kt + 1) << 6;
      #pragma unroll
      for (int q = 0; q < 4; ++q) {
        const int c = (w << 8) + (q << 6) + lane;
        const int row = c >> 3, sw = ((c & 7) ^ (row & 7)) << 3;
        __builtin_amdgcn_global_load_lds(
            (const AS1 void*)(A + (size_t)(m0 + row) * K + k1 + sw),
            (AS3 void*)(aN + (((w << 2) + q) << 9)), 16, 0, 0);
        __builtin_amdgcn_global_load_lds(
            (const AS1 void*)(B + (size_t)(n0 + row) * K + k1 + sw),
            (AS3 void*)(bN + (((w << 2) + q) << 9)), 16, 0, 0);
      }
    }
    #pragma unroll
    for (int ks = 0; ks < 2; ++ks) {
      bf8 af[4], bfr[4];
      #pragma unroll
      for (int i = 0; i < 4; ++i) {
        const int ra = wm + i * 16 + lr;
        const int rb = wn + i * 16 + lr;
        af[i]  = *(const bf8*)(aC + (ra << 6) + ((((ks << 2) + lg) ^ (ra & 7)) << 3));
        bfr[i] = *(const bf8*)(bC + (rb << 6) + ((((ks << 2) + lg) ^ (rb & 7)) << 3));
      }
      __builtin_amdgcn_s_setprio(1);
      #pragma unroll
      for (int i = 0; i < 4; ++i)
        #pragma unroll
        for (int j = 0; j < 4; ++j)
          acc[i][j] = __builtin_amdgcn_mfma_f32_16x16x32_bf16(af[i], bfr[j], acc[i][j], 0, 0, 0);
      __builtin_amdgcn_s_setprio(0);
    }
    __syncthreads();
  }

  gemm_epilogue<0>(acc, bias, (void*)C, 1024, 1.f, m0, n0, wm, wn, lr, lg);
}

// ---------------- flash attention: 3-buffer counted-vmcnt pipeline (R9) ------
__global__ __launch_bounds__(256, 3)
void attn_kernel(const u16* __restrict__ Qp, const u16* __restrict__ Kp,
                 const u16* __restrict__ VT, u16* __restrict__ Ob)
{
  __shared__ __align__(16) u16 pool[24576];     // 48 KB: kt[3][4096] | vt[3][4096]; reused as ot[128][72]
  u16* const ktb = pool;
  u16* const vtb = pool + 12288;

  const int flat = blockIdx.x;
  const int xcd = flat & 7, idx = flat >> 3;
  const int bh = (xcd << 3) + (idx >> 4);
  const int tq0 = (idx & 15) << 7;

  const int tid = threadIdx.x, lane = tid & 63, w = tid >> 6;
  const int ql = lane & 31, hi = lane >> 5;
  const size_t hoff = (size_t)bh * (2048 * 64);
  const u16* Kh = Kp + hoff;
  const u16* Vh = VT + hoff;

  bf8 qf[4];
  {
    const u16* qp_ = Qp + hoff + (size_t)(tq0 + w * 32 + ql) * 64 + hi * 8;
    #pragma unroll
    for (int ks = 0; ks < 4; ++ks) qf[ks] = *(const bf8*)(qp_ + 16 * ks);
  }

  f16v o0 = {}, o1 = {};
  float lrun = 0.f;

  const int c0i = (w << 7) + lane;
  const int c1i = c0i + 64;
  const int sr0 = c0i >> 3, ss0 = ((c0i & 7) ^ (sr0 & 7)) << 3;
  const int sr1 = c1i >> 3, ss1 = ((c1i & 7) ^ (sr1 & 7)) << 3;
  const int sd0 = (w << 10);
  const int sd1 = (w << 10) + 512;

  #define STAGE(buf, t0)                                                          \
    do {                                                                           \
      __builtin_amdgcn_global_load_lds((const AS1 void*)(Kh + (size_t)((t0) + sr0) * 64 + ss0), \
                                       (AS3 void*)(ktb + (buf) * 4096 + sd0), 16, 0, 0);  \
      __builtin_amdgcn_global_load_lds((const AS1 void*)(Kh + (size_t)((t0) + sr1) * 64 + ss1), \
                                       (AS3 void*)(ktb + (buf) * 4096 + sd1), 16, 0, 0);  \
      __builtin_amdgcn_global_load_lds((const AS1 void*)(Vh + (size_t)sr0 * 2048 + (t0) + ss0), \
                                       (AS3 void*)(vtb + (buf) * 4096 + sd0), 16, 0, 0);  \
      __builtin_amdgcn_global_load_lds((const AS1 void*)(Vh + (size_t)sr1 * 2048 + (t0) + ss1), \
                                       (AS3 void*)(vtb + (buf) * 4096 + sd1), 16, 0, 0);  \
    } while (0)

  STAGE(0, 0);
  STAGE(1, 64);

  const int xq = ql & 7;
  int bc = 0;
  for (int it = 0; it < 32; ++it) {
    if (it < 31) asm volatile("s_waitcnt vmcnt(4)" ::: "memory");
    else         asm volatile("s_waitcnt vmcnt(0)" ::: "memory");
    __builtin_amdgcn_s_barrier();
    __builtin_amdgcn_sched_barrier(0);

    if (it + 2 < 32) {
      const int bs = bc ? bc - 1 : 2;
      STAGE(bs, (it + 2) << 6);
    }

    const u16* kb = ktb + bc * 4096;
    const u16* vb = vtb + bc * 4096;

    f16v s0 = {}, s1 = {};
    #pragma unroll
    for (int ks = 0; ks < 4; ++ks) {
      bf8 kf0 = *(const bf8*)(kb + (ql << 6) + ((((ks << 1) + hi) ^ xq) << 3));
      bf8 kf1 = *(const bf8*)(kb + ((32 + ql) << 6) + ((((ks << 1) + hi) ^ xq) << 3));
      __builtin_amdgcn_s_setprio(1);
      s0 = __builtin_amdgcn_mfma_f32_32x32x16_bf16(kf0, qf[ks], s0, 0, 0, 0);
      s1 = __builtin_amdgcn_mfma_f32_32x32x16_bf16(kf1, qf[ks], s1, 0, 0, 0);
      __builtin_amdgcn_s_setprio(0);
    }

    bf8 vf0[4], vf1[4];
    #pragma unroll
    for (int ks = 0; ks < 4; ++ks) {
      vf0[ks] = *(const bf8*)(vb + (ql << 6) + ((((ks << 1) + hi) ^ xq) << 3));
      vf1[ks] = *(const bf8*)(vb + ((32 + ql) << 6) + ((((ks << 1) + hi) ^ xq) << 3));
    }

    float rs = 0.f;

    {
      unsigned wpk[8];
      #pragma unroll
      for (int i = 0; i < 8; ++i) {
        float e0 = __builtin_amdgcn_exp2f(s0[2 * i]);
        float e1 = __builtin_amdgcn_exp2f(s0[2 * i + 1]);
        rs += e0 + e1;
        wpk[i] = cvtpk(e0, e1);
      }
      swap32(wpk[0], wpk[2]); swap32(wpk[1], wpk[3]);
      swap32(wpk[4], wpk[6]); swap32(wpk[5], wpk[7]);
      bf8 pf0 = __builtin_bit_cast(bf8, make_uint4(wpk[0], wpk[1], wpk[2], wpk[3]));
      bf8 pf1 = __builtin_bit_cast(bf8, make_uint4(wpk[4], wpk[5], wpk[6], wpk[7]));
      __builtin_amdgcn_s_setprio(1);
      o0 = __builtin_amdgcn_mfma_f32_32x32x16_bf16(vf0[0], pf0, o0, 0, 0, 0);
      o1 = __builtin_amdgcn_mfma_f32_32x32x16_bf16(vf1[0], pf0, o1, 0, 0, 0);
      o0 = __builtin_amdgcn_mfma_f32_32x32x16_bf16(vf0[1], pf1, o0, 0, 0, 0);
      o1 = __builtin_amdgcn_mfma_f32_32x32x16_bf16(vf1[1], pf1, o1, 0, 0, 0);
      __builtin_amdgcn_s_setprio(0);
    }

    {
      unsigned wpk[8];
      #pragma unroll
      for (int i = 0; i < 8; ++i) {
        float e0 = __builtin_amdgcn_exp2f(s1[2 * i]);
        float e1 = __builtin_amdgcn_exp2f(s1[2 * i + 1]);
        rs += e0 + e1;
        wpk[i] = cvtpk(e0, e1);
      }
      swap32(wpk[0], wpk[2]); swap32(wpk[1], wpk[3]);
      swap32(wpk[4], wpk[6]); swap32(wpk[5], wpk[7]);
      bf8 pf2 = __builtin_bit_cast(bf8, make_uint4(wpk[0], wpk[1], wpk[2], wpk[3]));
      bf8 pf3 = __builtin_bit_cast(bf8, make_uint4(wpk[4], wpk[5], wpk[6], wpk[7]));
      __builtin_amdgcn_s_setprio(1);
      o0 = __builtin_amdgcn_mfma_f32_32x32x16_bf16(vf0[2], pf2, o0, 0, 0, 0);
      o1 = __builtin_amdgcn_mfma_f32_32x32x16_bf16(vf1[2], pf2, o1, 0, 0, 0);
      o0 = __builtin_amdgcn_mfma_f32_32x32x16_bf16(vf0[3], pf3, o0, 0, 0, 0);
      o1 = __builtin_amdgcn_mfma_f32_32x32x16_bf16(vf1[3], pf3, o1, 0, 0, 0);
      __builtin_amdgcn_s_setprio(0);
    }

    lrun += rs;
    bc = bc + 1 < 3 ? bc + 1 : 0;
  }
  #undef STAGE

  const float linv = 1.f / (lrun + __shfl_xor(lrun, 32));

  __syncthreads();
  u16* const ot = pool;
  const int orow = w * 32 + ql;
  #pragma unroll
  for (int c = 0; c < 2; ++c) {
    const f16v& o = c ? o1 : o0;
    #pragma unroll
    for (int g = 0; g < 4; ++g) {
      uint2 pk;
      pk.x = cvtpk(o[4 * g + 0] * linv, o[4 * g + 1] * linv);
      pk.y = cvtpk(o[4 * g + 2] * linv, o[4 * g + 3] * linv);
      *(uint2*)(ot + orow * 72 + 32 * c + 8 * g + 4 * hi) = pk;
    }
  }
  __syncthreads();

  const int b = bh >> 4, h = bh & 15;
  const int row = tid >> 1, seg = tid & 1;
  const u16* src = ot + row * 72 + seg * 32;
  u16* dst = Ob + ((size_t)(b * 2048 + tq0 + row) * 16 + h) * 64 + seg * 32;
  #pragma unroll
  for (int kk = 0; kk < 4; ++kk)
    *(uint4*)(dst + 8 * kk) = *(const uint4*)(src + 8 * kk);
}

// ---------------- host launch ----------------
extern "C" void kernel_launch(void* const* d_in, const int* in_sizes, int n_in,
                              void* d_out, int out_size, void* d_ws, size_t ws_size,
                              hipStream_t stream) {
  (void)in_sizes; (void)n_in; (void)out_size; (void)ws_size;
  const float* k_in = (const float*)d_in[0];
  const float* q_in = (const float*)d_in[1];
  const float* v_in = (const float*)d_in[2];
  const float* Wk = (const float*)d_in[3]; const float* bk = (const float*)d_in[4];
  const float* Wq = (const float*)d_in[5]; const float* bq = (const float*)d_in[6];
  const float* Wv = (const float*)d_in[7]; const float* bv = (const float*)d_in[8];
  const float* Wo = (const float*)d_in[9]; const float* bo = (const float*)d_in[10];
  float* out = (float*)d_out;

  char* ws = (char*)d_ws;
  const size_t SZ_ACT = (size_t)8192 * 1024 * 2;   // 16 MB bf16
  const size_t SZ_W   = (size_t)1024 * 1024 * 2;   // 2 MB bf16
  u16* Oc  = (u16*)(ws);
  u16* Qp  = (u16*)(ws + 1 * SZ_ACT);
  u16* Kp  = (u16*)(ws + 2 * SZ_ACT);
  u16* Vt  = (u16*)(ws + 3 * SZ_ACT);               // [B,H,CH,T]
  u16* Wqb = (u16*)(ws + 4 * SZ_ACT);
  u16* Wkb = (u16*)(ws + 4 * SZ_ACT + SZ_W);
  u16* Wvb = (u16*)(ws + 4 * SZ_ACT + 2 * SZ_W);
  u16* Wob = (u16*)(ws + 4 * SZ_ACT + 3 * SZ_W);

  // weights: one fused convert (outputs contiguous Wq|Wk|Wv|Wo)
  cvt4_kernel<<<4096, 256, 0, stream>>>(Wq, Wk, Wv, Wo, Wqb);

  const float c0 = 0.125f * 1.4426950408889634f;    // softmax scale * log2(e)

  // merged projections: Q (pre-scaled), K -> [B,H,T,CH]; V -> [B,H,CH,T]
  proj_qkv<<<1536, 256, 0, stream>>>(q_in, k_in, v_in, Wqb, Wkb, Wvb,
                                     bq, bk, bv, Qp, Kp, Vt, c0);

  // flash attention -> [B,T,C] bf16
  attn_kernel<<<1024, 256, 0, stream>>>(Qp, Kp, Vt, Oc);

  // output projection -> fp32
  gemm_out<<<512, 256, 0, stream>>>(Oc, Wob, bo, out);
}